// Round 12
// baseline (338.142 us; speedup 1.0000x reference)
//
#include <hip/hip_runtime.h>
#include <hip/hip_bf16.h>

#define DEVI __device__ __forceinline__

typedef float f32x4 __attribute__((ext_vector_type(4)));
typedef short bf16x8 __attribute__((ext_vector_type(8)));
typedef unsigned short u16x4 __attribute__((ext_vector_type(4)));

// B=16, H=16, N=1024, E=1024, D=64; M = B*N = 16384

DEVI unsigned short f2bf(float f) {
  union { float f; unsigned u; } v; v.f = f;
  unsigned r = v.u + 0x7fffu + ((v.u >> 16) & 1u);  // RNE
  return (unsigned short)(r >> 16);
}

DEVI float fexp2(float x) {
#if __has_builtin(__builtin_amdgcn_exp2f)
  return __builtin_amdgcn_exp2f(x);
#else
  return exp2f(x);
#endif
}

DEVI float frcp(float x) {
#if __has_builtin(__builtin_amdgcn_rcpf)
  return __builtin_amdgcn_rcpf(x);
#else
  return 1.0f / x;
#endif
}

DEVI unsigned cvtpk(float a, float b) {
  unsigned r;
  asm("v_cvt_pk_bf16_f32 %0, %1, %2" : "=v"(r) : "v"(a), "v"(b));
  return r;
}

DEVI void gload_lds16(const unsigned short* g, unsigned short* l) {
  __builtin_amdgcn_global_load_lds(
      (const __attribute__((address_space(1))) void*)g,
      (__attribute__((address_space(3))) void*)l, 16, 0, 0);
}

// workgroup barrier that does NOT drain vmcnt: LDS visibility only.
DEVI void wg_barrier() {
  asm volatile("s_waitcnt lgkmcnt(0)" ::: "memory");
  __builtin_amdgcn_s_barrier();
  __builtin_amdgcn_sched_barrier(0);
}

// ---------------- fused fp32 -> bf16 conversion (x + 4 weights, ONE dispatch) ----------------
__global__ void cvt_all(const float* __restrict__ x,
                        const float* __restrict__ Wq, const float* __restrict__ Wk,
                        const float* __restrict__ Wv, const float* __restrict__ Wp,
                        unsigned short* __restrict__ xbf, unsigned short* __restrict__ wbf) {
  int i = blockIdx.x * blockDim.x + threadIdx.x;
  const int st = gridDim.x * blockDim.x;
  for (; i < 5242880; i += st) {   // 4194304 (x) + 4 x 262144 (weights), in float4 units
    const float* s;
    unsigned short* d;
    int off;
    if (i < 4194304) {
      s = x; d = xbf; off = i;
    } else {
      const int j = i - 4194304;
      const int wsel = j >> 18;
      off = j & 262143;
      s = (wsel == 0) ? Wq : (wsel == 1) ? Wk : (wsel == 2) ? Wv : Wp;
      d = wbf + (wsel << 20);
    }
    const float4 v = reinterpret_cast<const float4*>(s)[off];
    u16x4 o;
    o[0] = f2bf(v.x); o[1] = f2bf(v.y); o[2] = f2bf(v.z); o[3] = f2bf(v.w);
    reinterpret_cast<u16x4*>(d)[off] = o;
  }
}

// ================= 256x256 8-phase counted-vmcnt GEMM mainloop =================
#define STA(BUF, C, K0) gload_lds16(&A[(size_t)(m0 + (C)*64 + srow) * 1024 + (K0) + scol], &lsA[BUF][(C)*4096 + tid*8])
#define STB(BUF, C, K0) gload_lds16(&Bw[(size_t)(n0 + (C)*64 + srow) * 1024 + (K0) + scol], &lsB[BUF][(C)*4096 + tid*8])

#define DSREAD_A(BUF, MF, KS) (*(const bf16x8*)&lsA[BUF][arow + (MF)*1024 + ((KS) ? sx1 : sx0)])
#define DSREAD_B(BUF, NF, KS) (*(const bf16x8*)&lsB[BUF][brow + (NF)*1024 + ((KS) ? sx1 : sx0)])

#define MFMA16(P, AF)                                                          \
    __builtin_amdgcn_s_setprio(1);                                             \
    _Pragma("unroll") for (int mfi = 0; mfi < 2; mfi++)                        \
      _Pragma("unroll") for (int nf = 0; nf < 4; nf++)                         \
        _Pragma("unroll") for (int ks = 0; ks < 2; ks++)                       \
          acc[2*(P)+mfi][nf] = __builtin_amdgcn_mfma_f32_16x16x32_bf16(        \
              AF[mfi][ks], bfr[nf][ks], acc[2*(P)+mfi][nf], 0, 0, 0);          \
    __builtin_amdgcn_s_setprio(0);

#define PHASE(BUF, P, LB, STG)                                                 \
  { __builtin_amdgcn_s_barrier();                                              \
    bf16x8 af[2][2];                                                           \
    _Pragma("unroll") for (int i = 0; i < 2; i++)                              \
      _Pragma("unroll") for (int k2 = 0; k2 < 2; k2++)                         \
        af[i][k2] = DSREAD_A(BUF, 2*(P)+i, k2);                                \
    if (LB) {                                                                  \
      _Pragma("unroll") for (int n2 = 0; n2 < 4; n2++)                         \
        _Pragma("unroll") for (int k2 = 0; k2 < 2; k2++)                       \
          bfr[n2][k2] = DSREAD_B(BUF, n2, k2);                                 \
    }                                                                          \
    STG;                                                                       \
    MFMA16(P, af) }

#define GSTEP(CB, NB, K1)                                                      \
    asm volatile("s_waitcnt vmcnt(2)" ::: "memory");                           \
    PHASE(CB, 0, 1, { STB(NB,0,K1); STB(NB,1,K1); })                           \
    PHASE(CB, 1, 0, { STB(NB,2,K1); STB(NB,3,K1); })                           \
    asm volatile("s_waitcnt vmcnt(4)" ::: "memory");                           \
    PHASE(CB, 2, 0, { STA(NB,0,K1); STA(NB,2,K1); })                           \
    PHASE(CB, 3, 0, { STA(NB,1,K1); STA(NB,3,K1); })

DEVI void gemm256_main(const unsigned short* __restrict__ A,
                       const unsigned short* __restrict__ Bw,
                       int m0, int n0,
                       unsigned short (&lsA)[2][16384],
                       unsigned short (&lsB)[2][16384],
                       f32x4 (&acc)[8][4]) {
  const int tid = threadIdx.x;
  const int l = tid & 63, lr = l & 15, lg = l >> 4;
  const int w = tid >> 6, wm = w >> 2, wn = w & 3;
  const int srow = tid >> 3;
  const int scol = (((tid & 7) ^ (srow & 7)) * 8);
  const int sx0 = (lg * 8) ^ ((lr & 7) << 3);
  const int sx1 = (32 + lg * 8) ^ ((lr & 7) << 3);
  const int arow = (wm * 128 + lr) * 64;
  const int brow = (wn * 64 + lr) * 64;

  STB(0,0,0); STB(0,1,0); STB(0,2,0); STB(0,3,0);
  STA(0,0,0); STA(0,1,0); STA(0,2,0); STA(0,3,0);
  asm volatile("s_waitcnt vmcnt(0)" ::: "memory");
  __builtin_amdgcn_s_barrier();

  bf16x8 bfr[4][2];

#pragma unroll 1
  for (int t7 = 0; t7 < 7; ++t7) {
    const int k1 = t7 * 128 + 64;
    GSTEP(0, 1, k1)
    GSTEP(1, 0, k1 + 64)
  }
  GSTEP(0, 1, 960)
  asm volatile("s_waitcnt vmcnt(2)" ::: "memory");
  PHASE(1, 0, 1, {})
  PHASE(1, 1, 0, {})
  asm volatile("s_waitcnt vmcnt(0)" ::: "memory");
  PHASE(1, 2, 0, {})
  PHASE(1, 3, 0, {})
}

// bijective XCD-chunk swizzle over the 256-wg (x,y) grid: 256 = 8 XCD x 32
DEVI void xcd_tile(int& m0, int& n0) {
  int f = blockIdx.y * 64 + blockIdx.x;
  f = (f & 7) * 32 + (f >> 3);
  m0 = (f & 63) * 256;
  n0 = (f >> 6) * 256;
}

// ---------------- QKV projection (8-phase 256^2) ----------------
// z=0: Q energy-B-frag tiles, pre-scaled by log2(e); z=1: K energy-A-frag tiles;
// z=2: V PV-B-frag tiles
__global__ __launch_bounds__(512, 2) void proj_qkv8(
    const unsigned short* __restrict__ A, const unsigned short* __restrict__ W3,
    const float* __restrict__ bq, const float* __restrict__ bk, const float* __restrict__ bv,
    unsigned short* __restrict__ outq, unsigned short* __restrict__ outk, unsigned short* __restrict__ outv) {
  __shared__ unsigned short lsA[2][16384];
  __shared__ unsigned short lsB[2][16384];
  const int z = blockIdx.z;
  int m0, n0;
  xcd_tile(m0, n0);
  const unsigned short* Bw = W3 + z * 1048576;
  f32x4 acc[8][4];
  const f32x4 z4 = {0.f, 0.f, 0.f, 0.f};
#pragma unroll
  for (int i = 0; i < 8; i++)
#pragma unroll
    for (int j = 0; j < 4; j++) acc[i][j] = z4;

  gemm256_main(A, Bw, m0, n0, lsA, lsB, acc);

  const int tid = threadIdx.x;
  const int l = tid & 63, lr = l & 15, lg = l >> 4;
  const int w = tid >> 6, wm = w >> 2, wn = w & 3;
  const float* bias = (z == 0) ? bq : ((z == 1) ? bk : bv);
  const float SC = 1.4426950408889634f;  // log2(e), folded into Q
#pragma unroll
  for (int mf = 0; mf < 8; mf++) {
    const int mb = m0 + wm * 128 + mf * 16 + lg * 4;
#pragma unroll
    for (int nf = 0; nf < 4; nf++) {
      const int ncol = n0 + wn * 64 + nf * 16 + lr;
      const float bsv = bias[ncol];
      const int h = ncol >> 6, d = ncol & 63;
      if (z == 0) {
        const int ks = d >> 5, lgq = (d >> 3) & 3, eq = d & 7;
#pragma unroll
        for (int r = 0; r < 4; r++) {
          const int m = mb + r;
          const int bb = m >> 10, nr = m & 1023;
          const int nt = nr >> 4, lrq = nr & 15;
          const int idx = (((bb * 64 + nt) * 32 + h * 2 + ks) * 64 + lgq * 16 + lrq) * 8 + eq;
          outq[idx] = f2bf((acc[mf][nf][r] + bsv) * SC);
        }
      } else if (z == 1) {
        const int ks = d >> 5, lhi = ((d >> 3) & 3) * 16, eq = d & 7;
#pragma unroll
        for (int r = 0; r < 4; r++) {
          const int m = mb + r;
          const int n = m & 1023, bx = m >> 10;
          const int lane = lhi + (n & 15);
          const int idx = ((((h * 64 + (n >> 4)) * 16 + bx) * 2 + ks) * 64 + lane) * 8 + eq;
          outk[idx] = f2bf(acc[mf][nf][r] + bsv);
        }
      } else {
        const int dt = d >> 4, lrv = d & 15;
        const int bb = mb >> 10, n = mb & 1023;
        const int kc = n >> 5, lgv = (n >> 3) & 3, ev = n & 7;
        u16x4 pk;
#pragma unroll
        for (int r = 0; r < 4; r++) pk[r] = f2bf(acc[mf][nf][r] + bsv);
        const int idx0 = ((((bb * 16 + h) * 32 + kc) * 4 + dt) * 64 + lgv * 16 + lrv) * 8 + ev;
        *(u16x4*)&outv[idx0] = pk;
      }
    }
  }
}

// ---------------- output projection (8-phase 256^2, fp32 out + bias) ----------------
__global__ __launch_bounds__(512, 2) void proj_out8(
    const unsigned short* __restrict__ A, const unsigned short* __restrict__ Wp,
    const float* __restrict__ bias, float* __restrict__ out) {
  __shared__ unsigned short lsA[2][16384];
  __shared__ unsigned short lsB[2][16384];
  int m0, n0;
  xcd_tile(m0, n0);
  f32x4 acc[8][4];
  const f32x4 z4 = {0.f, 0.f, 0.f, 0.f};
#pragma unroll
  for (int i = 0; i < 8; i++)
#pragma unroll
    for (int j = 0; j < 4; j++) acc[i][j] = z4;

  gemm256_main(A, Wp, m0, n0, lsA, lsB, acc);

  const int tid = threadIdx.x;
  const int l = tid & 63, lr = l & 15, lg = l >> 4;
  const int w = tid >> 6, wm = w >> 2, wn = w & 3;
#pragma unroll
  for (int mf = 0; mf < 8; mf++) {
    const int mb = m0 + wm * 128 + mf * 16 + lg * 4;
#pragma unroll
    for (int nf = 0; nf < 4; nf++) {
      const int ncol = n0 + wn * 64 + nf * 16 + lr;
      const float bsv = bias[ncol];
#pragma unroll
      for (int r = 0; r < 4; r++) out[(size_t)(mb + r) * 1024 + ncol] = acc[mf][nf][r] + bsv;
    }
  }
}

// ---------------- fused attention v12: 512-thr blocks, 2 barrier domains/CU ----------------
// 1024 blocks = b(16) x qt16(64); 2 blocks/CU (74 KB LDS) -> while one block
// waits at its exchange barrier, the other issues MFMA. 8 waves = 4 ksub x 2 hqg
// (energy: 8 heads x 16 q x 16 k each); h-sum = 2-way partner exchange.
// PV: wave owns heads {w, w+8}. Math identical to attn5 (p rounded once, f32).
__global__ __launch_bounds__(512, 4) void attn12(
    const unsigned short* __restrict__ Q2,  // [b][nt64][h*2+ks][lane][8]
    const unsigned short* __restrict__ K2,  // [hp][kt64][h_lab16][ks2][lane][8]
    const unsigned short* __restrict__ V2,  // [b*16+h][kc32][dt4][lane][8]
    unsigned short* __restrict__ O) {       // [16][1024][1024] natural
  __shared__ unsigned short qlds[16384];  // 32 KB Q fragments (loaded once)
  __shared__ unsigned short abuf[16384];  // 32 KB att [h16][q16][k64], XOR-swizzled
  __shared__ float sumbuf[2560];          // 10 KB: 8 tiles x 64 lanes x 4 (+pad)

  const int tid = threadIdx.x;
  const int w = tid >> 6, l = tid & 63;
  const int lr = l & 15, lg = l >> 4;
  const int bid = blockIdx.x;
  // residency round r = bid>>9 (512 blocks/round); within a round, XCD = bid&7
  // owns one batch: b = (bid>>9)*8 + (bid&7), qt16 = (bid>>3)&63.
  const int b = ((bid >> 9) << 3) + (bid & 7);
  const int qt16 = (bid >> 3) & 63;
  const int ksub = w & 3, hqg = w >> 2;  // energy role; PV role: heads {w, w+8}

  // ---- stage Q once: 32 KB contiguous ----
  {
    const unsigned short* qsrc = Q2 + (size_t)(b * 64 + qt16) * 16384 + tid * 8;
    unsigned short* qdst = qlds + tid * 8;
#pragma unroll
    for (int r = 0; r < 4; r++) gload_lds16(qsrc + r * 4096, qdst + r * 4096);
  }

  const int kpart = ksub * 16 + lg * 4;   // k-elem base of my 4 acc slots
  const int wswz = (lr & 7) << 3;
  const int myt = ksub * 2 + hqg, pat = ksub * 2 + (hqg ^ 1);

  const f32x4 z4 = {0.f, 0.f, 0.f, 0.f};
  f32x4 oacc[2][4];
#pragma unroll
  for (int hh = 0; hh < 2; hh++)
#pragma unroll
    for (int dt = 0; dt < 4; dt++) oacc[hh][dt] = z4;

  const unsigned short* kroot = K2 + (size_t)(b * 64 + ksub) * 16384 + hqg * 8192 + l * 8;
  const unsigned short* vroot = V2 + (size_t)((b * 16) * 32) * 2048 + l * 8;

  // Q staged via global_load_lds -> one full drain
  asm volatile("s_waitcnt vmcnt(0) lgkmcnt(0)" ::: "memory");
  __builtin_amdgcn_s_barrier();
  __builtin_amdgcn_sched_barrier(0);

#pragma unroll 1
  for (int it = 0; it < 16; it++) {
    int qo = 0;
    asm volatile("" : "+v"(qo));  // keep Q LDS reads inside the loop
    const unsigned short* kb = kroot + (size_t)(it * 4) * 16384;

    // ---- E: my 8 heads x 16 q x my 16 k (two 4-head passes bound registers) ----
    f32x4 e[8];
#pragma unroll
    for (int hp2 = 0; hp2 < 2; hp2++) {
      bf16x8 kr[8];
#pragma unroll
      for (int i = 0; i < 8; i++) kr[i] = *(const bf16x8*)(kb + hp2 * 4096 + i * 512);
#pragma unroll
      for (int hl = 0; hl < 4; hl++) {
        const int h = hqg * 8 + hp2 * 4 + hl;
        bf16x8 q0 = *(const bf16x8*)((const char*)qlds + qo + (h * 2 + 0) * 1024 + l * 16);
        bf16x8 q1 = *(const bf16x8*)((const char*)qlds + qo + (h * 2 + 1) * 1024 + l * 16);
        f32x4 t = __builtin_amdgcn_mfma_f32_16x16x32_bf16(kr[hl * 2 + 0], q0, z4, 0, 0, 0);
        t = __builtin_amdgcn_mfma_f32_16x16x32_bf16(kr[hl * 2 + 1], q1, t, 0, 0, 0);
        t[0] = fexp2(t[0]); t[1] = fexp2(t[1]); t[2] = fexp2(t[2]); t[3] = fexp2(t[3]);
        e[hp2 * 4 + hl] = t;
      }
    }
    // ---- 8-head partial sum; 2-way partner exchange ----
    f32x4 s = ((e[0] + e[1]) + (e[2] + e[3])) + ((e[4] + e[5]) + (e[6] + e[7]));
    *(f32x4*)&sumbuf[myt * 320 + l * 5] = s;
    wg_barrier();  // #1: partials visible; prev-iter pa reads done (att free)
    s += *(const f32x4*)&sumbuf[pat * 320 + l * 5];
    f32x4 inv;
    inv[0] = frcp(s[0]) * 0.03125f; inv[1] = frcp(s[1]) * 0.03125f;
    inv[2] = frcp(s[2]) * 0.03125f; inv[3] = frcp(s[3]) * 0.03125f;
    // ---- att writes (my 8 heads), p rounded ONCE from f32 ----
#pragma unroll
    for (int i = 0; i < 8; i++) {
      const int h = hqg * 8 + i;
      f32x4 vv = e[i] * inv;
      uint2 pk;
      pk.x = cvtpk(vv[0], vv[1]);
      pk.y = cvtpk(vv[2], vv[3]);
      *(uint2*)((char*)abuf + h * 2048 + lr * 128 + ((kpart ^ wswz) << 1)) = pk;
    }
    // V for first PV head in flight across the barrier
    bf16x8 vr[8];
    {
      const unsigned short* vb = vroot + (size_t)(w * 32 + it * 2) * 2048;
#pragma unroll
      for (int f = 0; f < 8; f++) vr[f] = *(const bf16x8*)(vb + f * 512);
    }
    wg_barrier();  // #2: att visible

    // ---- PV: head w, then head w+8 ----
    bf16x8 pa[2][2];
#pragma unroll
    for (int hh = 0; hh < 2; hh++)
#pragma unroll
      for (int kst = 0; kst < 2; kst++)
        pa[hh][kst] = *(const bf16x8*)((const char*)abuf + (w + hh * 8) * 2048 + lr * 128 +
                                       (((kst * 4 + lg) ^ (lr & 7)) << 4));
#pragma unroll
    for (int kst = 0; kst < 2; kst++)
#pragma unroll
      for (int dt = 0; dt < 4; dt++)
        oacc[0][dt] = __builtin_amdgcn_mfma_f32_16x16x32_bf16(pa[0][kst], vr[kst * 4 + dt], oacc[0][dt], 0, 0, 0);
    {
      const unsigned short* vb = vroot + (size_t)((w + 8) * 32 + it * 2) * 2048;
#pragma unroll
      for (int f = 0; f < 8; f++) vr[f] = *(const bf16x8*)(vb + f * 512);
    }
#pragma unroll
    for (int kst = 0; kst < 2; kst++)
#pragma unroll
      for (int dt = 0; dt < 4; dt++)
        oacc[1][dt] = __builtin_amdgcn_mfma_f32_16x16x32_bf16(pa[1][kst], vr[kst * 4 + dt], oacc[1][dt], 0, 0, 0);
  }

  // ---- epilogue: O natural [b][n][e], heads {w, w+8} ----
#pragma unroll
  for (int hh = 0; hh < 2; hh++) {
    const int h = w + hh * 8;
#pragma unroll
    for (int dt = 0; dt < 4; dt++)
#pragma unroll
      for (int r = 0; r < 4; r++) {
        const int n = qt16 * 16 + lg * 4 + r;
        O[(size_t)(b * 1024 + n) * 1024 + h * 64 + dt * 16 + lr] = f2bf(oacc[hh][dt][r]);
      }
  }
}

extern "C" void kernel_launch(void* const* d_in, const int* in_sizes, int n_in,
                              void* d_out, int out_size, void* d_ws, size_t ws_size,
                              hipStream_t stream) {
  const float* x  = (const float*)d_in[0];
  const float* Wq = (const float*)d_in[1];
  const float* bq = (const float*)d_in[2];
  const float* Wk = (const float*)d_in[3];
  const float* bk = (const float*)d_in[4];
  const float* Wv = (const float*)d_in[5];
  const float* bv = (const float*)d_in[6];
  const float* Wp = (const float*)d_in[7];
  const float* bp = (const float*)d_in[8];

  char* ws = (char*)d_ws;
  unsigned short* xbf  = (unsigned short*)(ws);              // 32 MiB; reused for O after attention
  unsigned short* qbf  = (unsigned short*)(ws + 33554432);   // Q2 fragment tiles
  unsigned short* kbf  = (unsigned short*)(ws + 67108864);   // K2 fragment tiles
  unsigned short* vtbf = (unsigned short*)(ws + 100663296);  // V2 fragment tiles
  unsigned short* wbf  = (unsigned short*)(ws + 134217728);  // Wq,Wk,Wv,Wp bf16 (4 x 2 MiB)

  cvt_all<<<5120, 256, 0, stream>>>(x, Wq, Wk, Wv, Wp, xbf, wbf);

  proj_qkv8<<<dim3(64, 4, 3), 512, 0, stream>>>(xbf, wbf, bq, bk, bv, qbf, kbf, vtbf);
  attn12<<<1024, 512, 0, stream>>>(qbf, kbf, vtbf, xbf);
  proj_out8<<<dim3(64, 4, 1), 512, 0, stream>>>(xbf, wbf + 3145728, bp, (float*)d_out);
}

// Round 13
// 323.612 us; speedup vs baseline: 1.0449x; 1.0449x over previous
//
#include <hip/hip_runtime.h>
#include <hip/hip_bf16.h>

#define DEVI __device__ __forceinline__

typedef float f32x4 __attribute__((ext_vector_type(4)));
typedef short bf16x8 __attribute__((ext_vector_type(8)));
typedef unsigned short u16x4 __attribute__((ext_vector_type(4)));

// B=16, H=16, N=1024, E=1024, D=64; M = B*N = 16384

DEVI unsigned short f2bf(float f) {
  union { float f; unsigned u; } v; v.f = f;
  unsigned r = v.u + 0x7fffu + ((v.u >> 16) & 1u);  // RNE
  return (unsigned short)(r >> 16);
}

DEVI float fexp2(float x) {
#if __has_builtin(__builtin_amdgcn_exp2f)
  return __builtin_amdgcn_exp2f(x);
#else
  return exp2f(x);
#endif
}

DEVI float frcp(float x) {
#if __has_builtin(__builtin_amdgcn_rcpf)
  return __builtin_amdgcn_rcpf(x);
#else
  return 1.0f / x;
#endif
}

DEVI unsigned cvtpk(float a, float b) {
  unsigned r;
  asm("v_cvt_pk_bf16_f32 %0, %1, %2" : "=v"(r) : "v"(a), "v"(b));
  return r;
}

DEVI void gload_lds16(const unsigned short* g, unsigned short* l) {
  __builtin_amdgcn_global_load_lds(
      (const __attribute__((address_space(1))) void*)g,
      (__attribute__((address_space(3))) void*)l, 16, 0, 0);
}

// workgroup barrier that does NOT drain vmcnt: LDS visibility only.
DEVI void wg_barrier() {
  asm volatile("s_waitcnt lgkmcnt(0)" ::: "memory");
  __builtin_amdgcn_s_barrier();
  __builtin_amdgcn_sched_barrier(0);
}

// ---------------- fused fp32 -> bf16 conversion (x + 4 weights, ONE dispatch) ----------------
__global__ void cvt_all(const float* __restrict__ x,
                        const float* __restrict__ Wq, const float* __restrict__ Wk,
                        const float* __restrict__ Wv, const float* __restrict__ Wp,
                        unsigned short* __restrict__ xbf, unsigned short* __restrict__ wbf) {
  int i = blockIdx.x * blockDim.x + threadIdx.x;
  const int st = gridDim.x * blockDim.x;
  for (; i < 5242880; i += st) {   // 4194304 (x) + 4 x 262144 (weights), in float4 units
    const float* s;
    unsigned short* d;
    int off;
    if (i < 4194304) {
      s = x; d = xbf; off = i;
    } else {
      const int j = i - 4194304;
      const int wsel = j >> 18;
      off = j & 262143;
      s = (wsel == 0) ? Wq : (wsel == 1) ? Wk : (wsel == 2) ? Wv : Wp;
      d = wbf + (wsel << 20);
    }
    const float4 v = reinterpret_cast<const float4*>(s)[off];
    u16x4 o;
    o[0] = f2bf(v.x); o[1] = f2bf(v.y); o[2] = f2bf(v.z); o[3] = f2bf(v.w);
    reinterpret_cast<u16x4*>(d)[off] = o;
  }
}

// ================= 256x256 8-phase counted-vmcnt GEMM mainloop =================
#define STA(BUF, C, K0) gload_lds16(&A[(size_t)(m0 + (C)*64 + srow) * 1024 + (K0) + scol], &lsA[BUF][(C)*4096 + tid*8])
#define STB(BUF, C, K0) gload_lds16(&Bw[(size_t)(n0 + (C)*64 + srow) * 1024 + (K0) + scol], &lsB[BUF][(C)*4096 + tid*8])

#define DSREAD_A(BUF, MF, KS) (*(const bf16x8*)&lsA[BUF][arow + (MF)*1024 + ((KS) ? sx1 : sx0)])
#define DSREAD_B(BUF, NF, KS) (*(const bf16x8*)&lsB[BUF][brow + (NF)*1024 + ((KS) ? sx1 : sx0)])

#define MFMA16(P, AF)                                                          \
    __builtin_amdgcn_s_setprio(1);                                             \
    _Pragma("unroll") for (int mfi = 0; mfi < 2; mfi++)                        \
      _Pragma("unroll") for (int nf = 0; nf < 4; nf++)                         \
        _Pragma("unroll") for (int ks = 0; ks < 2; ks++)                       \
          acc[2*(P)+mfi][nf] = __builtin_amdgcn_mfma_f32_16x16x32_bf16(        \
              AF[mfi][ks], bfr[nf][ks], acc[2*(P)+mfi][nf], 0, 0, 0);          \
    __builtin_amdgcn_s_setprio(0);

#define PHASE(BUF, P, LB, STG)                                                 \
  { __builtin_amdgcn_s_barrier();                                              \
    bf16x8 af[2][2];                                                           \
    _Pragma("unroll") for (int i = 0; i < 2; i++)                              \
      _Pragma("unroll") for (int k2 = 0; k2 < 2; k2++)                         \
        af[i][k2] = DSREAD_A(BUF, 2*(P)+i, k2);                                \
    if (LB) {                                                                  \
      _Pragma("unroll") for (int n2 = 0; n2 < 4; n2++)                         \
        _Pragma("unroll") for (int k2 = 0; k2 < 2; k2++)                       \
          bfr[n2][k2] = DSREAD_B(BUF, n2, k2);                                 \
    }                                                                          \
    STG;                                                                       \
    MFMA16(P, af) }

#define GSTEP(CB, NB, K1)                                                      \
    asm volatile("s_waitcnt vmcnt(2)" ::: "memory");                           \
    PHASE(CB, 0, 1, { STB(NB,0,K1); STB(NB,1,K1); })                           \
    PHASE(CB, 1, 0, { STB(NB,2,K1); STB(NB,3,K1); })                           \
    asm volatile("s_waitcnt vmcnt(4)" ::: "memory");                           \
    PHASE(CB, 2, 0, { STA(NB,0,K1); STA(NB,2,K1); })                           \
    PHASE(CB, 3, 0, { STA(NB,1,K1); STA(NB,3,K1); })

DEVI void gemm256_main(const unsigned short* __restrict__ A,
                       const unsigned short* __restrict__ Bw,
                       int m0, int n0,
                       unsigned short (&lsA)[2][16384],
                       unsigned short (&lsB)[2][16384],
                       f32x4 (&acc)[8][4]) {
  const int tid = threadIdx.x;
  const int l = tid & 63, lr = l & 15, lg = l >> 4;
  const int w = tid >> 6, wm = w >> 2, wn = w & 3;
  const int srow = tid >> 3;
  const int scol = (((tid & 7) ^ (srow & 7)) * 8);
  const int sx0 = (lg * 8) ^ ((lr & 7) << 3);
  const int sx1 = (32 + lg * 8) ^ ((lr & 7) << 3);
  const int arow = (wm * 128 + lr) * 64;
  const int brow = (wn * 64 + lr) * 64;

  STB(0,0,0); STB(0,1,0); STB(0,2,0); STB(0,3,0);
  STA(0,0,0); STA(0,1,0); STA(0,2,0); STA(0,3,0);
  asm volatile("s_waitcnt vmcnt(0)" ::: "memory");
  __builtin_amdgcn_s_barrier();

  bf16x8 bfr[4][2];

#pragma unroll 1
  for (int t7 = 0; t7 < 7; ++t7) {
    const int k1 = t7 * 128 + 64;
    GSTEP(0, 1, k1)
    GSTEP(1, 0, k1 + 64)
  }
  GSTEP(0, 1, 960)
  asm volatile("s_waitcnt vmcnt(2)" ::: "memory");
  PHASE(1, 0, 1, {})
  PHASE(1, 1, 0, {})
  asm volatile("s_waitcnt vmcnt(0)" ::: "memory");
  PHASE(1, 2, 0, {})
  PHASE(1, 3, 0, {})
}

// ---------------- QKV projection (8-phase 256^2), A-tile-consumer-adjacent grid ----------------
// flat 768 blocks; the 12 consumers (4 y x 3 z) of each 512 KB A-tile run
// temporally adjacent ON THE SAME XCD -> A-tile served from that XCD's L2.
__global__ __launch_bounds__(512, 2) void proj_qkv8(
    const unsigned short* __restrict__ A, const unsigned short* __restrict__ W3,
    const float* __restrict__ bq, const float* __restrict__ bk, const float* __restrict__ bv,
    unsigned short* __restrict__ outq, unsigned short* __restrict__ outk, unsigned short* __restrict__ outv) {
  __shared__ unsigned short lsA[2][16384];
  __shared__ unsigned short lsB[2][16384];
  const int f = blockIdx.x;
  const int flat = (f & 7) * 96 + (f >> 3);   // XCD c owns flat ids c*96..c*96+95 = 8 m-tiles
  const int mt = flat / 12, sub = flat - mt * 12;
  const int z = sub >> 2, y = sub & 3;
  const int m0 = mt * 256, n0 = y * 256;
  const unsigned short* Bw = W3 + z * 1048576;
  f32x4 acc[8][4];
  const f32x4 z4 = {0.f, 0.f, 0.f, 0.f};
#pragma unroll
  for (int i = 0; i < 8; i++)
#pragma unroll
    for (int j = 0; j < 4; j++) acc[i][j] = z4;

  gemm256_main(A, Bw, m0, n0, lsA, lsB, acc);

  const int tid = threadIdx.x;
  const int l = tid & 63, lr = l & 15, lg = l >> 4;
  const int w = tid >> 6, wm = w >> 2, wn = w & 3;
  const float* bias = (z == 0) ? bq : ((z == 1) ? bk : bv);
  const float SC = 1.4426950408889634f;  // log2(e), folded into Q
#pragma unroll
  for (int mf = 0; mf < 8; mf++) {
    const int mb = m0 + wm * 128 + mf * 16 + lg * 4;
#pragma unroll
    for (int nf = 0; nf < 4; nf++) {
      const int ncol = n0 + wn * 64 + nf * 16 + lr;
      const float bsv = bias[ncol];
      const int h = ncol >> 6, d = ncol & 63;
      if (z == 0) {
        const int ks = d >> 5, lgq = (d >> 3) & 3, eq = d & 7;
#pragma unroll
        for (int r = 0; r < 4; r++) {
          const int m = mb + r;
          const int bb = m >> 10, nr = m & 1023;
          const int nt = nr >> 4, lrq = nr & 15;
          const int idx = (((bb * 64 + nt) * 32 + h * 2 + ks) * 64 + lgq * 16 + lrq) * 8 + eq;
          outq[idx] = f2bf((acc[mf][nf][r] + bsv) * SC);
        }
      } else if (z == 1) {
        const int ks = d >> 5, lhi = ((d >> 3) & 3) * 16, eq = d & 7;
#pragma unroll
        for (int r = 0; r < 4; r++) {
          const int m = mb + r;
          const int n = m & 1023, bx = m >> 10;
          const int lane = lhi + (n & 15);
          const int idx = ((((h * 64 + (n >> 4)) * 16 + bx) * 2 + ks) * 64 + lane) * 8 + eq;
          outk[idx] = f2bf(acc[mf][nf][r] + bsv);
        }
      } else {
        const int dt = d >> 4, lrv = d & 15;
        const int bb = mb >> 10, n = mb & 1023;
        const int kc = n >> 5, lgv = (n >> 3) & 3, ev = n & 7;
        u16x4 pk;
#pragma unroll
        for (int r = 0; r < 4; r++) pk[r] = f2bf(acc[mf][nf][r] + bsv);
        const int idx0 = ((((bb * 16 + h) * 32 + kc) * 4 + dt) * 64 + lgv * 16 + lrv) * 8 + ev;
        *(u16x4*)&outv[idx0] = pk;
      }
    }
  }
}

// ---------------- output projection (8-phase 256^2, fp32 out + bias) ----------------
// same consumer-adjacent order: 4 y-consumers of each A-tile on one XCD.
__global__ __launch_bounds__(512, 2) void proj_out8(
    const unsigned short* __restrict__ A, const unsigned short* __restrict__ Wp,
    const float* __restrict__ bias, float* __restrict__ out) {
  __shared__ unsigned short lsA[2][16384];
  __shared__ unsigned short lsB[2][16384];
  const int f = blockIdx.x;
  const int flat = (f & 7) * 32 + (f >> 3);
  const int mt = flat >> 2, y = flat & 3;
  const int m0 = mt * 256, n0 = y * 256;
  f32x4 acc[8][4];
  const f32x4 z4 = {0.f, 0.f, 0.f, 0.f};
#pragma unroll
  for (int i = 0; i < 8; i++)
#pragma unroll
    for (int j = 0; j < 4; j++) acc[i][j] = z4;

  gemm256_main(A, Wp, m0, n0, lsA, lsB, acc);

  const int tid = threadIdx.x;
  const int l = tid & 63, lr = l & 15, lg = l >> 4;
  const int w = tid >> 6, wm = w >> 2, wn = w & 3;
#pragma unroll
  for (int mf = 0; mf < 8; mf++) {
    const int mb = m0 + wm * 128 + mf * 16 + lg * 4;
#pragma unroll
    for (int nf = 0; nf < 4; nf++) {
      const int ncol = n0 + wn * 64 + nf * 16 + lr;
      const float bsv = bias[ncol];
#pragma unroll
      for (int r = 0; r < 4; r++) out[(size_t)(mb + r) * 1024 + ncol] = acc[mf][nf][r] + bsv;
    }
  }
}

// ---------------- fused attention v5 (proven 163 us) ----------------
#define ATTN_BODY(IT, KC, KN)                                                  \
  {                                                                            \
    int qo = 0;                                                                \
    asm volatile("" : "+v"(qo));                                               \
    f32x4 e[4][2];                                                             \
    _Pragma("unroll") for (int hl = 0; hl < 4; hl++) {                         \
      const int h = hq * 4 + hl;                                               \
      _Pragma("unroll") for (int qh = 0; qh < 2; qh++) {                       \
        bf16x8 q0 = *(const bf16x8*)((const char*)qlds + qo + (qh * 32 + h * 2 + 0) * 1024 + l * 16); \
        bf16x8 q1 = *(const bf16x8*)((const char*)qlds + qo + (qh * 32 + h * 2 + 1) * 1024 + l * 16); \
        f32x4 t = __builtin_amdgcn_mfma_f32_16x16x32_bf16(KC[hl * 2 + 0], q0, z4, 0, 0, 0); \
        t = __builtin_amdgcn_mfma_f32_16x16x32_bf16(KC[hl * 2 + 1], q1, t, 0, 0, 0); \
        t[0] = fexp2(t[0]); t[1] = fexp2(t[1]); t[2] = fexp2(t[2]); t[3] = fexp2(t[3]); \
        e[hl][qh] = t;                                                         \
      }                                                                        \
    }                                                                          \
    {                                                                          \
      const unsigned short* knp = kroot + (size_t)((((IT) + 1) & 15) * 4) * 16384; \
      _Pragma("unroll") for (int i = 0; i < 8; i++) KN[i] = *(const bf16x8*)(knp + i * 512); \
    }                                                                          \
    f32x4 s0 = (e[0][0] + e[1][0]) + (e[2][0] + e[3][0]);                      \
    f32x4 s1 = (e[0][1] + e[1][1]) + (e[2][1] + e[3][1]);                      \
    *(f32x4*)&sumbuf[((ksub * 4 + hq) * 2 + 0) * 256 + l * 4] = s0;            \
    *(f32x4*)&sumbuf[((ksub * 4 + hq) * 2 + 1) * 256 + l * 4] = s1;            \
    wg_barrier();                                                              \
    _Pragma("unroll") for (int p = 1; p < 4; p++) {                            \
      const int hqp = hq ^ p;                                                  \
      s0 += *(const f32x4*)&sumbuf[((ksub * 4 + hqp) * 2 + 0) * 256 + l * 4];  \
      s1 += *(const f32x4*)&sumbuf[((ksub * 4 + hqp) * 2 + 1) * 256 + l * 4];  \
    }                                                                          \
    f32x4 inv0, inv1;                                                          \
    inv0[0] = frcp(s0[0]) * 0.03125f; inv0[1] = frcp(s0[1]) * 0.03125f;        \
    inv0[2] = frcp(s0[2]) * 0.03125f; inv0[3] = frcp(s0[3]) * 0.03125f;        \
    inv1[0] = frcp(s1[0]) * 0.03125f; inv1[1] = frcp(s1[1]) * 0.03125f;        \
    inv1[2] = frcp(s1[2]) * 0.03125f; inv1[3] = frcp(s1[3]) * 0.03125f;        \
    _Pragma("unroll") for (int hl = 0; hl < 4; hl++) {                         \
      const int h = hq * 4 + hl;                                               \
      _Pragma("unroll") for (int qh = 0; qh < 2; qh++) {                       \
        f32x4 vv = e[hl][qh] * (qh ? inv1 : inv0);                             \
        uint2 pk;                                                              \
        pk.x = cvtpk(vv[0], vv[1]);                                            \
        pk.y = cvtpk(vv[2], vv[3]);                                            \
        *(uint2*)((char*)abuf + h * 4096 + (qh * 16 + lr) * 128 + ((kpart ^ wswz) << 1)) = pk; \
      }                                                                        \
    }                                                                          \
    {                                                                          \
      const unsigned short* vbp = vroot + (size_t)((IT) * 2) * 2048;           \
      _Pragma("unroll") for (int kst = 0; kst < 2; kst++)                      \
        _Pragma("unroll") for (int dt = 0; dt < 4; dt++)                       \
          vr[kst * 4 + dt] = *(const bf16x8*)(vbp + kst * 2048 + dt * 512);    \
    }                                                                          \
    wg_barrier();                                                              \
    bf16x8 pa[2][2];                                                           \
    _Pragma("unroll") for (int qt = 0; qt < 2; qt++)                           \
      _Pragma("unroll") for (int kst = 0; kst < 2; kst++)                      \
        pa[qt][kst] = *(const bf16x8*)((const char*)abuf + w * 4096 + qt * 2048 + lr * 128 + (((kst * 4 + lg) ^ (lr & 7)) << 4)); \
    _Pragma("unroll") for (int qt = 0; qt < 2; qt++)                           \
      _Pragma("unroll") for (int kst = 0; kst < 2; kst++)                      \
        _Pragma("unroll") for (int dt = 0; dt < 4; dt++)                       \
          oacc[qt][dt] = __builtin_amdgcn_mfma_f32_16x16x32_bf16(pa[qt][kst], vr[kst * 4 + dt], oacc[qt][dt], 0, 0, 0); \
  }

__global__ __launch_bounds__(1024, 4) void attn5(
    const unsigned short* __restrict__ Q2,  // [b][nt64][h*2+ks][lane][8]
    const unsigned short* __restrict__ K2,  // [hp][kt64][h_lab16][ks2][lane][8]
    const unsigned short* __restrict__ V2,  // [b*16+h][kc32][dt4][lane][8]
    unsigned short* __restrict__ O) {       // [16][1024][1024] natural
  __shared__ unsigned short qlds[32768];  // 64 KB Q fragments (loaded once)
  __shared__ unsigned short abuf[32768];  // 64 KB att, XOR-swizzled
  __shared__ float sumbuf[8192];          // 32 KB partial h-sum exchange

  const int tid = threadIdx.x;
  const int w = tid >> 6, l = tid & 63;
  const int lr = l & 15, lg = l >> 4;
  const int bid = blockIdx.x;
  const int swz = (bid & 7) * 64 + (bid >> 3);  // XCD-chunked
  const int b = swz >> 5, qt32 = swz & 31;
  const int ksub = w & 3, hq = w >> 2;  // energy role; PV role: h = w

  // ---- stage Q once: 64 KB contiguous ----
  {
    const unsigned short* qsrc = Q2 + (size_t)(b * 64 + qt32 * 2) * 16384 + tid * 8;
    unsigned short* qdst = qlds + tid * 8;
#pragma unroll
    for (int r = 0; r < 4; r++) gload_lds16(qsrc + r * 8192, qdst + r * 8192);
  }

  const int kpart = ksub * 16 + lg * 4;   // k-elem base of my 4 acc slots
  const int wswz = (lr & 7) << 3;

  const f32x4 z4 = {0.f, 0.f, 0.f, 0.f};
  f32x4 oacc[2][4];
#pragma unroll
  for (int qt = 0; qt < 2; qt++)
#pragma unroll
    for (int dt = 0; dt < 4; dt++) oacc[qt][dt] = z4;

  const unsigned short* kroot = K2 + (size_t)(b * 64 + ksub) * 16384 + hq * 4096 + l * 8;
  const unsigned short* vroot = V2 + (size_t)((b * 16 + w) * 32) * 2048 + l * 8;

  // prologue: K[0] into regs (can issue before the Q barrier)
  bf16x8 kA[8], kB[8], vr[8];
#pragma unroll
  for (int i = 0; i < 8; i++) kA[i] = *(const bf16x8*)(kroot + i * 512);

  // Q staged via global_load_lds -> needs full vmcnt drain once
  asm volatile("s_waitcnt vmcnt(0) lgkmcnt(0)" ::: "memory");
  __builtin_amdgcn_s_barrier();
  __builtin_amdgcn_sched_barrier(0);

#pragma unroll 1
  for (int it2 = 0; it2 < 8; it2++) {
    ATTN_BODY(it2 * 2, kA, kB)
    ATTN_BODY(it2 * 2 + 1, kB, kA)
  }

  // ---- epilogue: O natural [b][n][e], my head h = w ----
#pragma unroll
  for (int qt = 0; qt < 2; qt++)
#pragma unroll
    for (int dt = 0; dt < 4; dt++)
#pragma unroll
      for (int r = 0; r < 4; r++) {
        const int n = qt32 * 32 + qt * 16 + lg * 4 + r;
        O[(size_t)(b * 1024 + n) * 1024 + w * 64 + dt * 16 + lr] = f2bf(oacc[qt][dt][r]);
      }
}

extern "C" void kernel_launch(void* const* d_in, const int* in_sizes, int n_in,
                              void* d_out, int out_size, void* d_ws, size_t ws_size,
                              hipStream_t stream) {
  const float* x  = (const float*)d_in[0];
  const float* Wq = (const float*)d_in[1];
  const float* bq = (const float*)d_in[2];
  const float* Wk = (const float*)d_in[3];
  const float* bk = (const float*)d_in[4];
  const float* Wv = (const float*)d_in[5];
  const float* bv = (const float*)d_in[6];
  const float* Wp = (const float*)d_in[7];
  const float* bp = (const float*)d_in[8];

  char* ws = (char*)d_ws;
  unsigned short* xbf  = (unsigned short*)(ws);              // 32 MiB; reused for O after attention
  unsigned short* qbf  = (unsigned short*)(ws + 33554432);   // Q2 fragment tiles
  unsigned short* kbf  = (unsigned short*)(ws + 67108864);   // K2 fragment tiles
  unsigned short* vtbf = (unsigned short*)(ws + 100663296);  // V2 fragment tiles
  unsigned short* wbf  = (unsigned short*)(ws + 134217728);  // Wq,Wk,Wv,Wp bf16 (4 x 2 MiB)

  cvt_all<<<5120, 256, 0, stream>>>(x, Wq, Wk, Wv, Wp, xbf, wbf);

  proj_qkv8<<<768, 512, 0, stream>>>(xbf, wbf, bq, bk, bv, qbf, kbf, vtbf);
  attn5<<<512, 1024, 0, stream>>>(qbf, kbf, vtbf, xbf);
  proj_out8<<<256, 512, 0, stream>>>(xbf, wbf + 3145728, bp, (float*)d_out);
}